// Round 5
// baseline (71.899 us; speedup 1.0000x reference)
//
#include <hip/hip_runtime.h>
#include <math.h>

// GLVQ, wave-owns-rows form.
// prep: x fp32->bf16 (+exact xsq), protos fp32->bf16 swizzled (+exact psq), zero out.
// main: 256 blocks x 128 thr; block DMAs all protos to LDS once; each wave computes
//       16 rows x ALL 128 protos (8 accs, 64 MFMAs) -> d1/d2 fully in-wave -> 1 barrier.
#define N_ROWS  8192
#define DIM     256
#define NPROTO  128

typedef float f32x4 __attribute__((ext_vector_type(4)));
typedef short s16x8 __attribute__((ext_vector_type(8)));

__device__ __forceinline__ unsigned short f2bf(float f) {
  unsigned int u = __float_as_uint(f);
  u += 0x7fffu + ((u >> 16) & 1u);
  return (unsigned short)(u >> 16);
}

__device__ __forceinline__ void gl_lds16(const void* g, void* l) {
  __builtin_amdgcn_global_load_lds(
      (const __attribute__((address_space(1))) void*)g,
      (__attribute__((address_space(3))) void*)l, 16, 0, 0);
}

// ---- prep: 512 blocks x 256 threads ----
// all blocks: 16 x-rows -> bf16 xbf + exact fp32 xsq
// blocks 0..15: additionally 8 proto rows -> swizzled bf16 pbf + exact psq
__global__ __launch_bounds__(256) void glvq_prep(
    const float* __restrict__ x, const float* __restrict__ proto,
    unsigned short* __restrict__ xbf, float* __restrict__ xsq,
    unsigned short* __restrict__ pbf, float* __restrict__ psq,
    float* __restrict__ out) {
  const int t = threadIdx.x;
  const int b = blockIdx.x;

  // x section: row = b*16 + (t>>4); thread owns 16 consecutive floats (i*16..)
  {
    const int r = b * 16 + (t >> 4);
    const int i = t & 15;
    const float4* xr = (const float4*)x + (size_t)r * 64 + i * 4;
    float4 v0 = xr[0], v1 = xr[1], v2 = xr[2], v3 = xr[3];
    union { s16x8 v; unsigned short u[8]; } pk0, pk1;
    pk0.u[0] = f2bf(v0.x); pk0.u[1] = f2bf(v0.y); pk0.u[2] = f2bf(v0.z); pk0.u[3] = f2bf(v0.w);
    pk0.u[4] = f2bf(v1.x); pk0.u[5] = f2bf(v1.y); pk0.u[6] = f2bf(v1.z); pk0.u[7] = f2bf(v1.w);
    pk1.u[0] = f2bf(v2.x); pk1.u[1] = f2bf(v2.y); pk1.u[2] = f2bf(v2.z); pk1.u[3] = f2bf(v2.w);
    pk1.u[4] = f2bf(v3.x); pk1.u[5] = f2bf(v3.y); pk1.u[6] = f2bf(v3.z); pk1.u[7] = f2bf(v3.w);
    *(s16x8*)&xbf[(size_t)r * 256 + i * 16] = pk0.v;
    *(s16x8*)&xbf[(size_t)r * 256 + i * 16 + 8] = pk1.v;
    float s = v0.x * v0.x + v0.y * v0.y + v0.z * v0.z + v0.w * v0.w +
              v1.x * v1.x + v1.y * v1.y + v1.z * v1.z + v1.w * v1.w +
              v2.x * v2.x + v2.y * v2.y + v2.z * v2.z + v2.w * v2.w +
              v3.x * v3.x + v3.y * v3.y + v3.z * v3.z + v3.w * v3.w;
#pragma unroll
    for (int m = 1; m <= 8; m <<= 1) s += __shfl_xor(s, m);  // 16-lane row reduce
    if (i == 0) xsq[r] = s;
  }

  // proto section (verified R4 scheme): swizzled slot = row*32 + (chunk ^ (row&7))
  if (b < 16) {
    const int tid = b * 256 + t;   // 0..4095 = 8-elem chunk id
    const int row = tid >> 5;
    const int co  = tid & 31;
    const float4* p4 = (const float4*)proto;
    float4 a = p4[tid * 2];
    float4 bb = p4[tid * 2 + 1];
    union { s16x8 v; unsigned short u[8]; } pk;
    pk.u[0] = f2bf(a.x);  pk.u[1] = f2bf(a.y);  pk.u[2] = f2bf(a.z);  pk.u[3] = f2bf(a.w);
    pk.u[4] = f2bf(bb.x); pk.u[5] = f2bf(bb.y); pk.u[6] = f2bf(bb.z); pk.u[7] = f2bf(bb.w);
    const int slot = row * 32 + (co ^ (row & 7));
    *(s16x8*)&pbf[slot * 8] = pk.v;
    float s = a.x * a.x + a.y * a.y + a.z * a.z + a.w * a.w +
              bb.x * bb.x + bb.y * bb.y + bb.z * bb.z + bb.w * bb.w;
#pragma unroll
    for (int m = 1; m <= 16; m <<= 1) s += __shfl_xor(s, m);  // 32-lane row reduce
    if (co == 0) psq[row] = s;
  }
  if (b == 0 && t == 0) out[0] = 0.f;
}

// ---- main: 256 blocks x 128 threads (2 waves); wave wv -> rows blk*32+wv*16.. ----
__global__ __launch_bounds__(128) void glvq_main(
    const unsigned short* __restrict__ xbf, const float* __restrict__ xsq_g,
    const int* __restrict__ y, const unsigned short* __restrict__ pbf,
    const float* __restrict__ psq_g, float* __restrict__ out) {
  __shared__ unsigned short pT[NPROTO * 256];  // 64 KB, swizzled bf16 protos

  const int t = threadIdx.x;
  // DMA all 128 protos: 32 x 16B/lane, verbatim copy of pre-swizzled layout
#pragma unroll
  for (int j = 0; j < 32; ++j) {
    const int c = j * 128 + t;  // 16B chunk 0..4095; lds = uniform base + lane*16
    gl_lds16((const char*)pbf + (size_t)c * 16, (char*)pT + (size_t)c * 16);
  }

  const int wv = t >> 6, l = t & 63, mq = l >> 4, mc = l & 15;
  const int row_base = blockIdx.x * 32 + wv * 16;

  // epilogue scalars + A-fragments: issue all before the barrier
  float xs[4]; int yr[4];
#pragma unroll
  for (int reg = 0; reg < 4; ++reg) {
    xs[reg] = xsq_g[row_base + mq * 4 + reg];
    yr[reg] = y[row_base + mq * 4 + reg];
  }
  float pq[8];
#pragma unroll
  for (int j = 0; j < 8; ++j) pq[j] = psq_g[j * 16 + mc];

  s16x8 afr[8];
  const unsigned short* xrow = xbf + (size_t)(row_base + mc) * 256;
#pragma unroll
  for (int ks = 0; ks < 8; ++ks)
    afr[ks] = *(const s16x8*)(xrow + ks * 32 + mq * 8);  // A[m=mc][k=32ks+8mq..]

  __syncthreads();  // drains proto DMA

  f32x4 acc[8];
#pragma unroll
  for (int j = 0; j < 8; ++j) acc[j] = (f32x4){0.f, 0.f, 0.f, 0.f};
  const int m7 = mc & 7;
#pragma unroll
  for (int ks = 0; ks < 8; ++ks) {
#pragma unroll
    for (int j = 0; j < 8; ++j) {
      const int p = j * 16 + mc;
      // swizzled chunk: slot = p*32 + ((4ks+mq) ^ (p&7)), p&7 == mc&7
      const s16x8 bf = *(const s16x8*)&pT[(p * 32 + ((4 * ks + mq) ^ m7)) * 8];
      acc[j] = __builtin_amdgcn_mfma_f32_16x16x32_bf16(afr[ks], bf, acc[j], 0, 0, 0);
    }
  }

  // epilogue, fully in-wave. C/D layout (m89): col=mc (proto), row=mq*4+reg.
  float ssum = 0.f;
#pragma unroll
  for (int reg = 0; reg < 4; ++reg) {
    float d1 = 1e30f, d2 = 1e30f;
#pragma unroll
    for (int j = 0; j < 8; ++j) {
      const float d = xs[reg] + pq[j] - 2.f * acc[j][reg];
      if (j * 16 + mc == yr[reg]) d1 = d; else d2 = fminf(d2, d);
    }
#pragma unroll
    for (int m = 1; m <= 8; m <<= 1) {  // reduce over the 16 mc-lanes
      d1 = fminf(d1, __shfl_xor(d1, m));
      d2 = fminf(d2, __shfl_xor(d2, m));
    }
    const float mu = (d1 - d2) / (d1 + d2);
    ssum += 1.f / (1.f + __expf(mu));  // sigmoid(-mu)
  }
  if (mc != 0) ssum = 0.f;        // dedupe: one contributor per mq group
  ssum += __shfl_xor(ssum, 16);   // sum the 4 mq groups
  ssum += __shfl_xor(ssum, 32);
  if (l == 0) atomicAdd(out, ssum * (1.f / (float)N_ROWS));
}

extern "C" void kernel_launch(void* const* d_in, const int* in_sizes, int n_in,
                              void* d_out, int out_size, void* d_ws, size_t ws_size,
                              hipStream_t stream) {
  const float* x = (const float*)d_in[0];       // [8192, 256] fp32
  const int* y = (const int*)d_in[1];           // [8192] int32
  const float* proto = (const float*)d_in[2];   // [128, 256] fp32
  float* out = (float*)d_out;                   // scalar fp32

  char* ws = (char*)d_ws;
  unsigned short* pbf = (unsigned short*)ws;                    // 64 KB swizzled protos
  unsigned short* xbf = (unsigned short*)(ws + 65536);          // 4 MB bf16 x
  float* xsq = (float*)(ws + 65536 + (size_t)N_ROWS * DIM * 2); // 32 KB
  float* psq = (float*)(ws + 65536 + (size_t)N_ROWS * DIM * 2 + N_ROWS * 4);  // 512 B

  glvq_prep<<<512, 256, 0, stream>>>(x, proto, xbf, xsq, pbf, psq, out);
  glvq_main<<<256, 128, 0, stream>>>(xbf, xsq, y, pbf, psq, out);
}

// Round 6
// 71.216 us; speedup vs baseline: 1.0096x; 1.0096x over previous
//
#include <hip/hip_runtime.h>
#include <math.h>

// GLVQ, fused form.
// prep (16 blocks): protos fp32 -> bf16 XOR-swizzled + exact psq + out=0.
// main (256 blocks x 128 thr): DMA protos->LDS; each wave: 16 rows x ALL 128 protos,
//   A-fragments converted fp32->bf16 in-register (no intermediate buffer), exact xsq
//   via mq-shuffles, 64 MFMAs, fully in-wave d1/d2 epilogue, one barrier, one atomic.
#define N_ROWS  8192
#define DIM     256
#define NPROTO  128

typedef float f32x4 __attribute__((ext_vector_type(4)));
typedef short s16x8 __attribute__((ext_vector_type(8)));

__device__ __forceinline__ unsigned short f2bf(float f) {
  unsigned int u = __float_as_uint(f);
  u += 0x7fffu + ((u >> 16) & 1u);
  return (unsigned short)(u >> 16);
}

__device__ __forceinline__ void gl_lds16(const void* g, void* l) {
  __builtin_amdgcn_global_load_lds(
      (const __attribute__((address_space(1))) void*)g,
      (__attribute__((address_space(3))) void*)l, 16, 0, 0);
}

// ---- prep: 16 blocks x 256 threads; slot = row*32 + (chunk ^ (row&7)) ----
__global__ __launch_bounds__(256) void glvq_prep(
    const float* __restrict__ proto, unsigned short* __restrict__ pbf,
    float* __restrict__ psq, float* __restrict__ out) {
  const int tid = blockIdx.x * 256 + threadIdx.x;  // 0..4095 = 8-elem chunk id
  const int row = tid >> 5;
  const int co  = tid & 31;
  const float4* p4 = (const float4*)proto;
  float4 a = p4[tid * 2];
  float4 b = p4[tid * 2 + 1];
  union { s16x8 v; unsigned short u[8]; } pk;
  pk.u[0] = f2bf(a.x); pk.u[1] = f2bf(a.y); pk.u[2] = f2bf(a.z); pk.u[3] = f2bf(a.w);
  pk.u[4] = f2bf(b.x); pk.u[5] = f2bf(b.y); pk.u[6] = f2bf(b.z); pk.u[7] = f2bf(b.w);
  const int slot = row * 32 + (co ^ (row & 7));
  *(s16x8*)&pbf[slot * 8] = pk.v;
  float s = a.x * a.x + a.y * a.y + a.z * a.z + a.w * a.w +
            b.x * b.x + b.y * b.y + b.z * b.z + b.w * b.w;
#pragma unroll
  for (int m = 1; m <= 16; m <<= 1) s += __shfl_xor(s, m);  // 32-lane row reduce
  if (co == 0) psq[row] = s;
  if (tid == 0) out[0] = 0.f;
}

// ---- main: 256 blocks x 128 threads (2 waves); wave -> rows blk*32 + wv*16 .. ----
__global__ __launch_bounds__(128) void glvq_main(
    const float* __restrict__ x, const int* __restrict__ y,
    const unsigned short* __restrict__ pbf, const float* __restrict__ psq_g,
    float* __restrict__ out) {
  __shared__ unsigned short pT[NPROTO * 256];  // 64 KB swizzled bf16 protos

  const int t = threadIdx.x;
  // DMA all protos: 32 x 16B/lane, verbatim copy of pre-swizzled layout (async)
#pragma unroll
  for (int j = 0; j < 32; ++j) {
    const int c = j * 128 + t;
    gl_lds16((const char*)pbf + (size_t)c * 16, (char*)pT + (size_t)c * 16);
  }

  const int wv = t >> 6, l = t & 63, mq = l >> 4, mc = l & 15;
  const int row_base = blockIdx.x * 32 + wv * 16;

  // A-fragments in-register: lane (mq,mc) owns x[row_base+mc][32ks+8mq .. +7]
  // (per-ks the wave touches 16 rows x 128 contiguous bytes -> full 128B lines)
  s16x8 afr[8];
  float sx = 0.f;
  {
    const float4* xr = (const float4*)x + (size_t)(row_base + mc) * 64;
#pragma unroll
    for (int ks = 0; ks < 8; ++ks) {
      float4 a = xr[ks * 8 + mq * 2];
      float4 b = xr[ks * 8 + mq * 2 + 1];
      union { s16x8 v; unsigned short u[8]; } pk;
      pk.u[0] = f2bf(a.x); pk.u[1] = f2bf(a.y); pk.u[2] = f2bf(a.z); pk.u[3] = f2bf(a.w);
      pk.u[4] = f2bf(b.x); pk.u[5] = f2bf(b.y); pk.u[6] = f2bf(b.z); pk.u[7] = f2bf(b.w);
      afr[ks] = pk.v;
      sx += a.x * a.x + a.y * a.y + a.z * a.z + a.w * a.w +
            b.x * b.x + b.y * b.y + b.z * b.z + b.w * b.w;
    }
  }
  // exact xsq for row (row_base+mc): sum the 4 mq-partials (lanes differ in bits 4-5)
  sx += __shfl_xor(sx, 16);
  sx += __shfl_xor(sx, 32);
  // distribute: epilogue reg needs row mq*4+reg, held (reduced) by lane mq*4+reg
  float xs[4]; int yr[4];
  const int yv = y[row_base + mc];  // lane mc owns row mc's label
#pragma unroll
  for (int reg = 0; reg < 4; ++reg) {
    xs[reg] = __shfl(sx, mq * 4 + reg);
    yr[reg] = __shfl(yv, mq * 4 + reg);
  }
  float pq[8];
#pragma unroll
  for (int j = 0; j < 8; ++j) pq[j] = psq_g[j * 16 + mc];

  __syncthreads();  // drains proto DMA

  f32x4 acc[8];
#pragma unroll
  for (int j = 0; j < 8; ++j) acc[j] = (f32x4){0.f, 0.f, 0.f, 0.f};
  const int m7 = mc & 7;
#pragma unroll
  for (int ks = 0; ks < 8; ++ks) {
#pragma unroll
    for (int j = 0; j < 8; ++j) {
      const int p = j * 16 + mc;
      // swizzled chunk: slot = p*32 + ((4ks+mq) ^ (p&7)); p&7 == mc&7
      const s16x8 bf = *(const s16x8*)&pT[(p * 32 + ((4 * ks + mq) ^ m7)) * 8];
      acc[j] = __builtin_amdgcn_mfma_f32_16x16x32_bf16(afr[ks], bf, acc[j], 0, 0, 0);
    }
  }

  // epilogue, in-wave. C/D layout (m89): col=mc (proto), row=mq*4+reg.
  float ssum = 0.f;
#pragma unroll
  for (int reg = 0; reg < 4; ++reg) {
    float d1 = 1e30f, d2 = 1e30f;
#pragma unroll
    for (int j = 0; j < 8; ++j) {
      const float d = xs[reg] + pq[j] - 2.f * acc[j][reg];
      if (j * 16 + mc == yr[reg]) d1 = d; else d2 = fminf(d2, d);
    }
#pragma unroll
    for (int m = 1; m <= 8; m <<= 1) {  // min over the 16 mc-lanes
      d1 = fminf(d1, __shfl_xor(d1, m));
      d2 = fminf(d2, __shfl_xor(d2, m));
    }
    const float mu = (d1 - d2) / (d1 + d2);
    ssum += 1.f / (1.f + __expf(mu));  // sigmoid(-mu)
  }
  if (mc != 0) ssum = 0.f;        // one contributor per mq group
  ssum += __shfl_xor(ssum, 16);   // sum 4 mq groups
  ssum += __shfl_xor(ssum, 32);
  if (l == 0) atomicAdd(out, ssum * (1.f / (float)N_ROWS));
}

extern "C" void kernel_launch(void* const* d_in, const int* in_sizes, int n_in,
                              void* d_out, int out_size, void* d_ws, size_t ws_size,
                              hipStream_t stream) {
  const float* x = (const float*)d_in[0];       // [8192, 256] fp32
  const int* y = (const int*)d_in[1];           // [8192] int32
  const float* proto = (const float*)d_in[2];   // [128, 256] fp32
  float* out = (float*)d_out;                   // scalar fp32

  unsigned short* pbf = (unsigned short*)d_ws;             // 64 KB swizzled bf16 protos
  float* psq = (float*)((char*)d_ws + NPROTO * DIM * 2);   // 512 B psq

  glvq_prep<<<16, 256, 0, stream>>>(proto, pbf, psq, out);
  glvq_main<<<256, 128, 0, stream>>>(x, y, pbf, psq, out);
}